// Round 6
// baseline (449.846 us; speedup 1.0000x reference)
//
#include <hip/hip_runtime.h>
#include <hip/hip_bf16.h>

// ---------------- constants ----------------
#define B_SZ   4
#define SEQ    2048
#define DM     1024
#define DIN    2048
#define DST    64
#define NH     32
#define HD     64
#define CONVD  2176
#define DPROJ  4256   // 2*DIN + 2*DST + NH
#define NPAD1  4352   // DPROJ padded to 34*128
#define MROWS  (B_SZ*SEQ)  // 8192
#define QC     64     // scan chunk length
#define NC     (SEQ/QC)   // 32 chunks

typedef __attribute__((ext_vector_type(8))) __bf16 bf16x8;
typedef __attribute__((ext_vector_type(4))) __bf16 bf16x4;
typedef __attribute__((ext_vector_type(4))) float  floatx4;

// XOR-swizzled index into a 64x64 bf16 LDS tile (8-elem granules rotated by row&7)
__device__ __forceinline__ int swz(int row, int col) {
    return row * 64 + ((((col >> 3) ^ (row & 7)) << 3) | (col & 7));
}
__device__ __forceinline__ float bfbits2f(unsigned short u) {
    return __uint_as_float(((unsigned int)u) << 16);
}
__device__ __forceinline__ unsigned short f2bfbits(float f) {
    union { __bf16 h; unsigned short u; } cv; cv.h = (__bf16)f; return cv.u;
}

// ---------------- compact dt-weight: dtWc[k*32+h] = W_in[k][4224+h] ----------------
__global__ __launch_bounds__(256) void dtw_prep_kernel(const float* __restrict__ W_in,
                                                       float* __restrict__ dtWc) {
    int idx = blockIdx.x * 256 + threadIdx.x;     // 32768 total
    int k = idx >> 5, h = idx & 31;
    dtWc[idx] = W_in[(size_t)k * DPROJ + 2 * DIN + 2 * DST + h];
}

// ---------------- fused: x -> bf16 copy + fp32 dt projection ----------------
__global__ __launch_bounds__(256) void cvt_dt_kernel(const float* __restrict__ x,
                                                     const float* __restrict__ dtWc,
                                                     __bf16* __restrict__ xbf,
                                                     float* __restrict__ dtraw) {
    __shared__ float xs[4][DM];
    __shared__ float red[4][8][32];
    const int row0 = blockIdx.x * 4;
    const int tid = threadIdx.x;
    #pragma unroll
    for (int r = 0; r < 4; r++) {
        float4 v = ((const float4*)(x + (size_t)(row0 + r) * DM))[tid];
        bf16x4 o;
        o[0] = (__bf16)v.x; o[1] = (__bf16)v.y; o[2] = (__bf16)v.z; o[3] = (__bf16)v.w;
        *(bf16x4*)(xbf + (size_t)(row0 + r) * DM + tid * 4) = o;
        xs[r][tid * 4 + 0] = v.x; xs[r][tid * 4 + 1] = v.y;
        xs[r][tid * 4 + 2] = v.z; xs[r][tid * 4 + 3] = v.w;
    }
    __syncthreads();
    const int part = tid >> 5, h = tid & 31;
    const float* wb = dtWc + part * 128 * 32 + h;
    const int kb = part * 128;
    float s0 = 0.f, s1 = 0.f, s2 = 0.f, s3 = 0.f;
    for (int j = 0; j < 128; j++) {
        float w = wb[j * 32];
        s0 = fmaf(xs[0][kb + j], w, s0);
        s1 = fmaf(xs[1][kb + j], w, s1);
        s2 = fmaf(xs[2][kb + j], w, s2);
        s3 = fmaf(xs[3][kb + j], w, s3);
    }
    red[0][part][h] = s0; red[1][part][h] = s1;
    red[2][part][h] = s2; red[3][part][h] = s3;
    __syncthreads();
    if (tid < 128) {
        int r = tid >> 5, hh = tid & 31;
        float s = 0.f;
        #pragma unroll
        for (int p = 0; p < 8; p++) s += red[r][p][hh];
        dtraw[(size_t)(row0 + r) * NH + hh] = s;
    }
}

// ---------------- transpose + cast: dst[c][r] = bf16(src[r][c]) (0 for c>=C) ----
__global__ __launch_bounds__(256) void transpose_cvt_kernel(const float* __restrict__ src,
                                                            __bf16* __restrict__ dst,
                                                            int R, int C, int Crows) {
    __shared__ float tile[32][33];
    int r0 = blockIdx.x * 32, c0 = blockIdx.y * 32;
    int tx = threadIdx.x & 31, ty = threadIdx.x >> 5;  // 32 x 8
    #pragma unroll
    for (int i = 0; i < 4; i++) {
        int r = r0 + ty + i * 8, c = c0 + tx;
        float v = (r < R && c < C) ? src[(size_t)r * C + c] : 0.f;
        tile[ty + i * 8][tx] = v;
    }
    __syncthreads();
    #pragma unroll
    for (int i = 0; i < 4; i++) {
        int cc = c0 + ty + i * 8, rr = r0 + tx;
        if (cc < Crows && rr < R)
            dst[(size_t)cc * R + rr] = (__bf16)tile[tx][ty + i * 8];
    }
}

// ---------------- bf16 MFMA GEMM: C[M][N] = A[M][K] * Bt[N][K]^T ----------------
// LDS tiles stored in MFMA-fragment order: chunk c (16B) = A[(c>>6)*16 + (c&15)][((c&63)>>4)*8 ...]
// so ds_read_b128 for fragments is lane-linear -> conflict-free.
template<int STORE_BF16>
__global__ __launch_bounds__(256) void gemm_bt_kernel(const __bf16* __restrict__ A,
                                                      const __bf16* __restrict__ Bt,
                                                      float* __restrict__ Cf,
                                                      __bf16* __restrict__ Cb,
                                                      int M, int N, int K) {
    __shared__ __align__(16) __bf16 As[4096];
    __shared__ __align__(16) __bf16 Bs[4096];
    const int tid = threadIdx.x;
    const int m0 = blockIdx.x * 128, n0 = blockIdx.y * 128;
    const int wave = tid >> 6, lane = tid & 63;
    const int lm = lane & 15, lq = lane >> 4;

    floatx4 acc[4][4] = {};

    for (int k0 = 0; k0 < K; k0 += 32) {
        #pragma unroll
        for (int r = 0; r < 2; r++) {
            int c = tid + (r << 8);              // 512 chunks of 16 B
            int ln = c & 63;
            int row = ((c >> 6) << 4) + (ln & 15);
            int off = (ln >> 4) << 3;
            __builtin_amdgcn_global_load_lds(
                reinterpret_cast<const unsigned int*>(&A[(size_t)(m0 + row) * K + k0 + off]),
                reinterpret_cast<unsigned int*>(As + (size_t)c * 8), 16, 0, 0);
            __builtin_amdgcn_global_load_lds(
                reinterpret_cast<const unsigned int*>(&Bt[(size_t)(n0 + row) * K + k0 + off]),
                reinterpret_cast<unsigned int*>(Bs + (size_t)c * 8), 16, 0, 0);
        }
        __syncthreads();
        bf16x8 af[4], bfr[4];
        #pragma unroll
        for (int i = 0; i < 4; i++)
            af[i] = *(const bf16x8*)(As + ((((wave & 1) << 2) + i) << 9) + (lane << 3));
        #pragma unroll
        for (int i = 0; i < 4; i++)
            bfr[i] = *(const bf16x8*)(Bs + ((((wave >> 1) << 2) + i) << 9) + (lane << 3));
        #pragma unroll
        for (int mi = 0; mi < 4; mi++)
            #pragma unroll
            for (int ni = 0; ni < 4; ni++)
                acc[mi][ni] = __builtin_amdgcn_mfma_f32_16x16x32_bf16(af[mi], bfr[ni], acc[mi][ni], 0, 0, 0);
        __syncthreads();
    }

    const int wm = (wave & 1) << 6, wn = (wave >> 1) << 6;
    #pragma unroll
    for (int mi = 0; mi < 4; mi++) {
        #pragma unroll
        for (int r = 0; r < 4; r++) {
            int row = m0 + wm + mi * 16 + lq * 4 + r;
            #pragma unroll
            for (int ni = 0; ni < 4; ni++) {
                int col = n0 + wn + ni * 16 + lm;
                if (col < N) {
                    if (STORE_BF16) Cb[(size_t)row * N + col] = (__bf16)acc[mi][ni][r];
                    else            Cf[(size_t)row * N + col] = acc[mi][ni][r];
                }
            }
        }
    }
}

// ---------------- depthwise causal conv (width 4) + silu, vectorized bf16x8 ----------
// thread = 8 channels x 8 timesteps.  grid (17, 64), block 256.
__global__ __launch_bounds__(256) void conv_silu_kernel(const __bf16* __restrict__ zx,
                                                        const float* __restrict__ cw,
                                                        const float* __restrict__ cb,
                                                        __bf16* __restrict__ out) {
    const int tid = threadIdx.x;
    const int tc = tid & 15, tt = tid >> 4;
    const int c0 = (blockIdx.x * 16 + tc) * 8;      // 0..2168
    const int tg = blockIdx.y * 16 + tt;            // 0..1023
    const int b = tg >> 8, t0 = (tg & 255) << 3;

    float xb[11][8];
    #pragma unroll
    for (int i = 0; i < 11; i++) {
        int t = t0 + i - 3;
        if (t >= 0) {
            bf16x8 v = *(const bf16x8*)(zx + ((size_t)(b * SEQ + t)) * DPROJ + DIN + c0);
            #pragma unroll
            for (int j = 0; j < 8; j++) xb[i][j] = (float)v[j];
        } else {
            #pragma unroll
            for (int j = 0; j < 8; j++) xb[i][j] = 0.f;
        }
    }
    float w0[8], w1[8], w2[8], w3[8], bias[8];
    #pragma unroll
    for (int j = 0; j < 8; j++) {
        float4 w = *(const float4*)(cw + (size_t)(c0 + j) * 4);
        w0[j] = w.x; w1[j] = w.y; w2[j] = w.z; w3[j] = w.w;
        bias[j] = cb[c0 + j];
    }
    #pragma unroll
    for (int s = 0; s < 8; s++) {
        bf16x8 o;
        #pragma unroll
        for (int j = 0; j < 8; j++) {
            float v = bias[j] + w0[j] * xb[s][j] + w1[j] * xb[s + 1][j]
                              + w2[j] * xb[s + 2][j] + w3[j] * xb[s + 3][j];
            o[j] = (__bf16)(v / (1.f + __expf(-v)));
        }
        *(bf16x8*)(out + ((size_t)(b * SEQ + t0 + s)) * CONVD + c0) = o;
    }
}

// ---------------- dt prep: softplus + per-chunk inclusive cumsum of dt*A ----------------
__global__ __launch_bounds__(256) void dt_prep_kernel(const float* __restrict__ dtraw,
                                                      const float* __restrict__ dt_bias,
                                                      const float* __restrict__ A_log,
                                                      float* __restrict__ dtv,
                                                      float* __restrict__ cum) {
    int blk = blockIdx.x;          // b*NH + h
    int b = blk >> 5, h = blk & 31;
    int wave = threadIdx.x >> 6, lane = threadIdx.x & 63;
    float Ah = -__expf(A_log[h]);
    float dtb = dt_bias[h];
    for (int c = wave; c < NC; c += 4) {
        int t = c * QC + lane;
        float u = dtraw[((size_t)b * SEQ + t) * NH + h] + dtb;
        float d = fmaxf(u, 0.f) + log1pf(__expf(-fabsf(u)));  // softplus, fp32
        float s = d * Ah;
        #pragma unroll
        for (int o = 1; o < 64; o <<= 1) {        // inclusive wave prefix sum
            float v = __shfl_up(s, o);
            if (lane >= o) s += v;
        }
        size_t idx = (size_t)blk * SEQ + t;
        dtv[idx] = d;
        cum[idx] = s;
    }
}

// ---------------- chunk state (MFMA): S^T[p][n] = sum_s x[s][p]*w_s*B[s][n] ----------
__global__ __launch_bounds__(256) void chunk_state_kernel(const __bf16* __restrict__ xc,
                                                          const float* __restrict__ dtv,
                                                          const float* __restrict__ cum,
                                                          __bf16* __restrict__ Sbuf) {
    const int blk = blockIdx.x;            // ((b*NC)+c)*8 + hq
    const int hq = blk & 7;
    const int bc = blk >> 3;
    const int c = bc & (NC - 1), b = bc >> 5;
    const int tid = threadIdx.x;
    const int wave = tid >> 6, lane = tid & 63;
    const int lm = lane & 15, q = lane >> 4;
    const int h = hq * 4 + wave;

    __shared__ __align__(16) __bf16 sBt[4096];      // B^T [n][s], swizzled
    __shared__ __align__(16) __bf16 sXw[4][4096];   // (w*x)^T [p][s], swizzled

    const size_t rowbase = (size_t)b * SEQ + (size_t)c * QC;
    {
        int k = tid & 31, n0 = (tid >> 5) * 8;
        unsigned short u0[8], u1[8];
        *(uint4*)u0 = *(const uint4*)(xc + (rowbase + 2 * k) * CONVD + DIN + n0);
        *(uint4*)u1 = *(const uint4*)(xc + (rowbase + 2 * k + 1) * CONVD + DIN + n0);
        #pragma unroll
        for (int i = 0; i < 8; i++) {
            unsigned int v = (unsigned int)u0[i] | ((unsigned int)u1[i] << 16);
            ((unsigned int*)sBt)[swz(n0 + i, 2 * k) >> 1] = v;
        }
    }
    const float* cump = cum + (size_t)(b * NH + h) * SEQ + (size_t)c * QC;
    const float* dtp  = dtv + (size_t)(b * NH + h) * SEQ + (size_t)c * QC;
    {
        int k = lane & 31, ph = (lane >> 5) * 32;
        float clast = cump[63];
        float w0 = dtp[2 * k]     * __expf(clast - cump[2 * k]);
        float w1 = dtp[2 * k + 1] * __expf(clast - cump[2 * k + 1]);
        unsigned short u0[32], u1[32];
        const __bf16* r0 = xc + (rowbase + 2 * k) * CONVD + h * 64 + ph;
        const __bf16* r1 = xc + (rowbase + 2 * k + 1) * CONVD + h * 64 + ph;
        #pragma unroll
        for (int i = 0; i < 4; i++) {
            ((uint4*)u0)[i] = ((const uint4*)r0)[i];
            ((uint4*)u1)[i] = ((const uint4*)r1)[i];
        }
        unsigned int* dstw = (unsigned int*)sXw[wave];
        #pragma unroll
        for (int i = 0; i < 32; i++) {
            unsigned int lo = f2bfbits(bfbits2f(u0[i]) * w0);
            unsigned int hi = f2bfbits(bfbits2f(u1[i]) * w1);
            dstw[swz(ph + i, 2 * k) >> 1] = lo | (hi << 16);
        }
    }
    __syncthreads();

    floatx4 acc[4][4] = {};
    #pragma unroll
    for (int kb = 0; kb < 2; kb++) {
        bf16x8 aX[4], bB[4];
        #pragma unroll
        for (int pi = 0; pi < 4; pi++)
            aX[pi] = *(const bf16x8*)(&sXw[wave][swz(pi * 16 + lm, kb * 32 + q * 8)]);
        #pragma unroll
        for (int ni = 0; ni < 4; ni++)
            bB[ni] = *(const bf16x8*)(&sBt[swz(ni * 16 + lm, kb * 32 + q * 8)]);
        #pragma unroll
        for (int pi = 0; pi < 4; pi++)
            #pragma unroll
            for (int ni = 0; ni < 4; ni++)
                acc[pi][ni] = __builtin_amdgcn_mfma_f32_16x16x32_bf16(aX[pi], bB[ni], acc[pi][ni], 0, 0, 0);
    }
    __bf16* Sp = Sbuf + ((size_t)(b * NC + c) * NH + h) * (HD * DST);
    #pragma unroll
    for (int pi = 0; pi < 4; pi++)
        #pragma unroll
        for (int r = 0; r < 4; r++) {
            int p = pi * 16 + q * 4 + r;
            #pragma unroll
            for (int ni = 0; ni < 4; ni++)
                Sp[p * 64 + ni * 16 + lm] = (__bf16)acc[pi][ni][r];
        }
}

// ---------------- pass 2: inter-chunk state recurrence (in place) ----------------
__global__ __launch_bounds__(256) void state_scan_kernel(__bf16* __restrict__ Sbuf,
                                                         const float* __restrict__ cum) {
    int blk = blockIdx.x;          // b*NH + h
    int b = blk >> 5, h = blk & 31;
    int off = threadIdx.x * 16;
    float run[16];
    #pragma unroll
    for (int n = 0; n < 16; n++) run[n] = 0.f;
    for (int c = 0; c < NC; c++) {
        __bf16* Sp = Sbuf + ((size_t)(b * NC + c) * NH + h) * (HD * DST) + off;
        float tmp[16];
        #pragma unroll
        for (int n = 0; n < 16; n++) tmp[n] = (float)Sp[n];
        #pragma unroll
        for (int n = 0; n < 16; n++) Sp[n] = (__bf16)run[n];   // slot c <- state before chunk c
        float P = __expf(cum[(size_t)blk * SEQ + c * QC + QC - 1]);
        #pragma unroll
        for (int n = 0; n < 16; n++) run[n] = fmaf(run[n], P, tmp[n]);
    }
}

// ---------------- chunk output (MFMA): Y = exp(cum_t)*C@S_prev + (M o C@B^T + D*I)@X
// block = (b,c,head-pair); wave = one head; 128 threads; 32 KB LDS (P aliases B/C).
__global__ __launch_bounds__(128) void chunk_out_kernel(const __bf16* __restrict__ xc,
                                                        const float* __restrict__ dtv,
                                                        const float* __restrict__ cum,
                                                        const __bf16* __restrict__ Sbuf,
                                                        const float* __restrict__ Dv,
                                                        __bf16* __restrict__ y) {
    const int blk = blockIdx.x;           // ((b*NC)+c)*16 + hp
    const int hp = blk & 15;
    const int bc = blk >> 4;
    const int c = bc & (NC - 1), b = bc >> 5;
    const int tid = threadIdx.x;
    const int wave = tid >> 6, lane = tid & 63;
    const int lm = lane & 15, q = lane >> 4;
    const int h = hp * 2 + wave;

    __shared__ __align__(16) __bf16 smem[16384];     // 32 KB
    __bf16* sB  = smem;                              // B [s][n] swizzled (shared)
    __bf16* sC  = smem + 4096;                       // C [t][n] swizzled (shared)
    __bf16* sXt = smem + 8192 + (wave << 12);        // x^T [p][s] swizzled (per wave)
    __bf16* sP  = smem + (wave << 12);               // P aliases sB (w0) / sC (w1)

    const size_t rowbase = (size_t)b * SEQ + (size_t)c * QC;
    {
        int r = tid >> 1, c0 = (tid & 1) * 32;
        const __bf16* gB = xc + (rowbase + r) * CONVD + DIN + c0;
        const __bf16* gC = xc + (rowbase + r) * CONVD + DIN + DST + c0;
        #pragma unroll
        for (int i = 0; i < 4; i++) {
            *(uint4*)(&sB[swz(r, c0 + i * 8)]) = *(const uint4*)(gB + i * 8);
            *(uint4*)(&sC[swz(r, c0 + i * 8)]) = *(const uint4*)(gC + i * 8);
        }
    }
    {
        int k = lane & 31, ph = (lane >> 5) * 32;
        unsigned short u0[32], u1[32];
        const __bf16* r0 = xc + (rowbase + 2 * k) * CONVD + h * 64 + ph;
        const __bf16* r1 = xc + (rowbase + 2 * k + 1) * CONVD + h * 64 + ph;
        #pragma unroll
        for (int i = 0; i < 4; i++) {
            ((uint4*)u0)[i] = ((const uint4*)r0)[i];
            ((uint4*)u1)[i] = ((const uint4*)r1)[i];
        }
        unsigned int* dstw = (unsigned int*)sXt;
        #pragma unroll
        for (int i = 0; i < 32; i++)
            dstw[swz(ph + i, 2 * k) >> 1] = (unsigned int)u0[i] | ((unsigned int)u1[i] << 16);
    }
    __syncthreads();

    const float* cump = cum + (size_t)(b * NH + h) * SEQ + (size_t)c * QC;
    const float* dtp  = dtv + (size_t)(b * NH + h) * SEQ + (size_t)c * QC;
    float cumv = cump[lane], dtvv = dtp[lane];
    float ct[4][4];
    #pragma unroll
    for (int ti = 0; ti < 4; ti++)
        #pragma unroll
        for (int r = 0; r < 4; r++)
            ct[ti][r] = __shfl(cumv, ti * 16 + q * 4 + r);
    float cums_l[4], dtv_l[4];
    #pragma unroll
    for (int si = 0; si < 4; si++) {
        cums_l[si] = __shfl(cumv, si * 16 + lm);
        dtv_l[si]  = __shfl(dtvv, si * 16 + lm);
    }

    // A-fragments of C (reused for G and inter GEMMs)
    bf16x8 afC[4][2];
    #pragma unroll
    for (int ti = 0; ti < 4; ti++)
        #pragma unroll
        for (int kb = 0; kb < 2; kb++)
            afC[ti][kb] = *(const bf16x8*)(&sC[swz(ti * 16 + lm, kb * 32 + q * 8)]);

    // G = C @ B^T (triangular tiles si<=ti)
    floatx4 accG[4][4] = {};
    #pragma unroll
    for (int kb = 0; kb < 2; kb++) {
        bf16x8 bfB[4];
        #pragma unroll
        for (int si = 0; si < 4; si++)
            bfB[si] = *(const bf16x8*)(&sB[swz(si * 16 + lm, kb * 32 + q * 8)]);
        #pragma unroll
        for (int ti = 0; ti < 4; ti++)
            #pragma unroll
            for (int si = 0; si < 4; si++)
                if (si <= ti)
                    accG[ti][si] = __builtin_amdgcn_mfma_f32_16x16x32_bf16(afC[ti][kb], bfB[si], accG[ti][si], 0, 0, 0);
    }
    __syncthreads();   // all waves done reading sB/sC -> safe to overwrite with P

    // mask + decay -> P (bf16, swizzled [t][s]); D folded onto the diagonal
    float Dh = Dv[h];
    #pragma unroll
    for (int ti = 0; ti < 4; ti++)
        #pragma unroll
        for (int si = 0; si < 4; si++) {
            if (si > ti) continue;
            #pragma unroll
            for (int r = 0; r < 4; r++) {
                int t = ti * 16 + q * 4 + r;
                float arg = fminf(ct[ti][r] - cums_l[si], 0.f);
                float val = dtv_l[si] * __expf(arg) * accG[ti][si][r];
                if (ti == si) {
                    if (lm > q * 4 + r) val = 0.f;
                    else if (lm == q * 4 + r) val += Dh;
                }
                sP[swz(t, si * 16 + lm)] = (__bf16)val;
            }
        }
    #pragma unroll
    for (int r = 0; r < 4; r++) {   // zero tiles (0,1) and (2,3)
        sP[swz(q * 4 + r, 16 + lm)] = (__bf16)0.f;
        sP[swz(32 + q * 4 + r, 48 + lm)] = (__bf16)0.f;
    }
    __syncthreads();

    // inter-chunk: Y = C @ S_prev, then row-scale by exp(cum_t)
    floatx4 accY[4][4] = {};
    const __bf16* Sp = Sbuf + ((size_t)(b * NC + c) * NH + h) * (HD * DST);
    #pragma unroll
    for (int kb = 0; kb < 2; kb++) {
        bf16x8 bS[4];
        #pragma unroll
        for (int pi = 0; pi < 4; pi++)
            bS[pi] = *(const bf16x8*)(Sp + (pi * 16 + lm) * 64 + kb * 32 + q * 8);
        #pragma unroll
        for (int ti = 0; ti < 4; ti++)
            #pragma unroll
            for (int pi = 0; pi < 4; pi++)
                accY[ti][pi] = __builtin_amdgcn_mfma_f32_16x16x32_bf16(afC[ti][kb], bS[pi], accY[ti][pi], 0, 0, 0);
    }
    #pragma unroll
    for (int ti = 0; ti < 4; ti++)
        #pragma unroll
        for (int r = 0; r < 4; r++) {
            float e = __expf(ct[ti][r]);
            #pragma unroll
            for (int pi = 0; pi < 4; pi++)
                accY[ti][pi][r] *= e;
        }

    // intra: Y += P @ X  (skip fully-masked k-blocks)
    #pragma unroll
    for (int kb = 0; kb < 2; kb++) {
        bf16x8 bX[4];
        #pragma unroll
        for (int pi = 0; pi < 4; pi++)
            bX[pi] = *(const bf16x8*)(&sXt[swz(pi * 16 + lm, kb * 32 + q * 8)]);
        #pragma unroll
        for (int ti = 0; ti < 4; ti++) {
            if (ti < 2 * kb) continue;
            bf16x8 aP = *(const bf16x8*)(&sP[swz(ti * 16 + lm, kb * 32 + q * 8)]);
            #pragma unroll
            for (int pi = 0; pi < 4; pi++)
                accY[ti][pi] = __builtin_amdgcn_mfma_f32_16x16x32_bf16(aP, bX[pi], accY[ti][pi], 0, 0, 0);
        }
    }

    // store
    #pragma unroll
    for (int ti = 0; ti < 4; ti++)
        #pragma unroll
        for (int r = 0; r < 4; r++) {
            int t = ti * 16 + q * 4 + r;
            __bf16* yrow = y + (rowbase + t) * DIN + h * 64;
            #pragma unroll
            for (int pi = 0; pi < 4; pi++)
                yrow[pi * 16 + lm] = (__bf16)accY[ti][pi][r];
        }
}

// ---------------- gate (silu(z)) + RMSNorm, IN PLACE on y (bf16, vectorized) -------
__global__ __launch_bounds__(256) void gate_norm_kernel(__bf16* __restrict__ y,
                                                        const __bf16* __restrict__ zx,
                                                        const float* __restrict__ nw) {
    int row = blockIdx.x;
    int tid = threadIdx.x;
    __bf16* yr = y + (size_t)row * DIN + tid * 8;
    const __bf16* zr = zx + (size_t)row * DPROJ + tid * 8;
    bf16x8 yv = *(const bf16x8*)yr;
    bf16x8 zv = *(const bf16x8*)zr;
    float v[8]; float ss = 0.f;
    #pragma unroll
    for (int j = 0; j < 8; j++) {
        float z = (float)zv[j];
        float val = (float)yv[j] * (z / (1.f + __expf(-z)));
        v[j] = val; ss += val * val;
    }
    __shared__ float red[4];
    int lane = tid & 63, wave = tid >> 6;
    for (int o = 32; o > 0; o >>= 1) ss += __shfl_down(ss, o);
    if (lane == 0) red[wave] = ss;
    __syncthreads();
    float tot = red[0] + red[1] + red[2] + red[3];
    float scale = rsqrtf(tot * (1.f / (float)DIN) + 1e-5f);
    const float* nwp = nw + tid * 8;
    bf16x8 o;
    #pragma unroll
    for (int j = 0; j < 8; j++) o[j] = (__bf16)(v[j] * scale * nwp[j]);
    *(bf16x8*)yr = o;
}

// ---------------- launch ----------------
extern "C" void kernel_launch(void* const* d_in, const int* in_sizes, int n_in,
                              void* d_out, int out_size, void* d_ws, size_t ws_size,
                              hipStream_t stream) {
    const float* x       = (const float*)d_in[0];
    const float* W_in    = (const float*)d_in[1];
    const float* conv_w  = (const float*)d_in[2];
    const float* conv_b  = (const float*)d_in[3];
    const float* dt_bias = (const float*)d_in[4];
    const float* A_log   = (const float*)d_in[5];
    const float* Dv      = (const float*)d_in[6];
    const float* norm_w  = (const float*)d_in[7];
    const float* W_out   = (const float*)d_in[8];
    float* out = (float*)d_out;

    char* ws = (char*)d_ws;
    size_t off = 0;
    auto take = [&](size_t bytes) { void* p = ws + off; off = (off + bytes + 255) & ~(size_t)255; return p; };
    __bf16* xbf    = (__bf16*)take((size_t)MROWS * DM * 2);          // 16.8 MB
    __bf16* WinT   = (__bf16*)take((size_t)NPAD1 * DM * 2);          //  8.9 MB
    __bf16* WoutT  = (__bf16*)take((size_t)DM * DIN * 2);            //  4.2 MB
    __bf16* zx     = (__bf16*)take((size_t)MROWS * DPROJ * 2);       // 69.7 MB
    __bf16* xc     = (__bf16*)take((size_t)MROWS * CONVD * 2);       // 35.7 MB
    __bf16* yf     = (__bf16*)take((size_t)MROWS * DIN * 2);         // 33.6 MB
    float*  dtraw  = (float*) take((size_t)MROWS * NH * 4);          //  1.0 MB
    float*  dtv    = (float*) take((size_t)B_SZ * NH * SEQ * 4);     //  1.0 MB
    float*  cum    = (float*) take((size_t)B_SZ * NH * SEQ * 4);     //  1.0 MB
    __bf16* Sbuf   = (__bf16*)take((size_t)B_SZ * NC * NH * HD * DST * 2); // 33.6 MB
    float*  dtWc   = (float*) take((size_t)DM * NH * 4);             //  0.13 MB
    (void)ws_size;                                                    // total ~206 MB

    // 1. compact dt-weight
    dtw_prep_kernel<<<dim3(DM * NH / 256), 256, 0, stream>>>(W_in, dtWc);
    // 2. fused x->bf16 + fp32 dt projection
    cvt_dt_kernel<<<dim3(MROWS / 4), 256, 0, stream>>>(x, dtWc, xbf, dtraw);
    // 3. W_in^T (pad to 4352 rows of zeros), W_out^T
    transpose_cvt_kernel<<<dim3(DM / 32, NPAD1 / 32), 256, 0, stream>>>(W_in, WinT, DM, DPROJ, NPAD1);
    transpose_cvt_kernel<<<dim3(DIN / 32, DM / 32), 256, 0, stream>>>(W_out, WoutT, DIN, DM, DM);
    // 4. GEMM1: zx = x @ W_in  (bf16 out)
    gemm_bt_kernel<1><<<dim3(MROWS / 128, (DPROJ + 127) / 128), 256, 0, stream>>>(
        xbf, WinT, nullptr, zx, MROWS, DPROJ, DM);
    // 5. depthwise conv + silu (vectorized)
    conv_silu_kernel<<<dim3(17, 64), 256, 0, stream>>>(zx, conv_w, conv_b, xc);
    // 6. dt prep: softplus + per-chunk cumsum
    dt_prep_kernel<<<dim3(B_SZ * NH), 256, 0, stream>>>(dtraw, dt_bias, A_log, dtv, cum);
    // 7. chunk-local states via MFMA (1024 blocks x 4 waves)
    chunk_state_kernel<<<dim3(B_SZ * NC * (NH / 4)), 256, 0, stream>>>(xc, dtv, cum, Sbuf);
    // 8. inter-chunk state recurrence
    state_scan_kernel<<<dim3(B_SZ * NH), 256, 0, stream>>>(Sbuf, cum);
    // 9. chunk outputs via MFMA (2048 blocks x 2 waves)
    chunk_out_kernel<<<dim3(B_SZ * NC * (NH / 2)), 128, 0, stream>>>(xc, dtv, cum, Sbuf, Dv, yf);
    // 10. gate + RMSNorm (in place on yf)
    gate_norm_kernel<<<dim3(MROWS), 256, 0, stream>>>(yf, zx, norm_w);
    // 11. GEMM2: out = yf @ W_out (fp32 out)
    gemm_bt_kernel<0><<<dim3(MROWS / 128, DM / 128), 256, 0, stream>>>(
        yf, WoutT, out, nullptr, MROWS, DM, DIN);
}

// Round 7
// 402.904 us; speedup vs baseline: 1.1165x; 1.1165x over previous
//
#include <hip/hip_runtime.h>
#include <hip/hip_bf16.h>

// ---------------- constants ----------------
#define B_SZ   4
#define SEQ    2048
#define DM     1024
#define DIN    2048
#define DST    64
#define NH     32
#define HD     64
#define CONVD  2176
#define DPROJ  4256   // 2*DIN + 2*DST + NH
#define NPAD1  4352   // DPROJ padded to 34*128
#define MROWS  (B_SZ*SEQ)  // 8192
#define QC     64     // scan chunk length
#define NC     (SEQ/QC)   // 32 chunks

// Tiled operand layout for MFMA GEMMs ("fragment order"):
//   flat(r,k) = (((r>>4)*(K>>5) + (k>>5))*64 + ((k>>3)&3)*16 + (r&15))*8 + (k&7)
// => each (16-row, 32-col) tile is 512 contiguous elems, lane-linear for both
//    global_load_lds staging and ds_read_b128 fragment reads.

typedef __attribute__((ext_vector_type(8))) __bf16 bf16x8;
typedef __attribute__((ext_vector_type(4))) __bf16 bf16x4;
typedef __attribute__((ext_vector_type(4))) float  floatx4;

// XOR-swizzled index into a 64x64 bf16 LDS tile (8-elem granules rotated by row&7)
__device__ __forceinline__ int swz(int row, int col) {
    return row * 64 + ((((col >> 3) ^ (row & 7)) << 3) | (col & 7));
}
__device__ __forceinline__ float bfbits2f(unsigned short u) {
    return __uint_as_float(((unsigned int)u) << 16);
}
__device__ __forceinline__ unsigned short f2bfbits(float f) {
    union { __bf16 h; unsigned short u; } cv; cv.h = (__bf16)f; return cv.u;
}

// ---------------- compact dt-weight: dtWc[k*32+h] = W_in[k][4224+h] ----------------
__global__ __launch_bounds__(256) void dtw_prep_kernel(const float* __restrict__ W_in,
                                                       float* __restrict__ dtWc) {
    int idx = blockIdx.x * 256 + threadIdx.x;     // 32768 total
    int k = idx >> 5, h = idx & 31;
    dtWc[idx] = W_in[(size_t)k * DPROJ + 2 * DIN + 2 * DST + h];
}

// ---------------- fused: x -> TILED bf16 copy + fp32 dt projection ----------------
// block = one 16-row slab (M/16 = 512 blocks); K=1024 processed in 8 chunks of 128.
__global__ __launch_bounds__(256) void cvt_dt_kernel(const float* __restrict__ x,
                                                     const float* __restrict__ dtWc,
                                                     __bf16* __restrict__ xbf,
                                                     float* __restrict__ dtraw) {
    __shared__ float xs[16][132];
    __shared__ float dtw[128 * 32];
    const int tid = threadIdx.x;
    const int r0 = blockIdx.x * 16;
    const int lm = tid & 15, pos = tid >> 4;              // granule writer mapping
    const int rr = tid >> 4, h2 = (tid & 15) * 2;         // dt accumulator mapping
    __bf16* slab = xbf + (size_t)blockIdx.x * (16 * DM);  // slab = 16*K contiguous

    float a0 = 0.f, a1 = 0.f;
    for (int kc = 0; kc < 8; kc++) {
        // stage 16 rows x 128 cols of x (fp32) + the matching dtWc rows
        #pragma unroll
        for (int i = 0; i < 2; i++) {
            int idx = tid + 256 * i;                       // 512 float4
            int row = idx >> 5, c4 = idx & 31;
            float4 v = ((const float4*)(x + (size_t)(r0 + row) * DM + kc * 128))[c4];
            xs[row][c4 * 4 + 0] = v.x; xs[row][c4 * 4 + 1] = v.y;
            xs[row][c4 * 4 + 2] = v.z; xs[row][c4 * 4 + 3] = v.w;
        }
        #pragma unroll
        for (int i = 0; i < 16; i++)
            dtw[tid + 256 * i] = dtWc[kc * 4096 + tid + 256 * i];
        __syncthreads();
        // write one granule (16B) to tiled xbf: row lm, cols pos*8..+7 of this chunk
        {
            bf16x8 o;
            #pragma unroll
            for (int e = 0; e < 8; e++) o[e] = (__bf16)xs[lm][pos * 8 + e];
            int kb = kc * 4 + (pos >> 2), q = pos & 3;
            *(bf16x8*)(slab + (size_t)(kb * 64 + q * 16 + lm) * 8) = o;
        }
        // dt partial sums: thread owns (row rr, heads h2,h2+1)
        for (int j = 0; j < 128; j++) {
            float xv = xs[rr][j];
            a0 = fmaf(xv, dtw[j * 32 + h2], a0);
            a1 = fmaf(xv, dtw[j * 32 + h2 + 1], a1);
        }
        __syncthreads();
    }
    dtraw[(size_t)(r0 + rr) * NH + h2]     = a0;
    dtraw[(size_t)(r0 + rr) * NH + h2 + 1] = a1;
}

// ---------------- transpose + cast -> TILED bf16: dst_tiled[n][k] = src[k][n] --------
// grid (Npad/128, Ksrc/32); block 256.
__global__ __launch_bounds__(256) void transpose_tiled_kernel(const float* __restrict__ src,
                                                              __bf16* __restrict__ dst,
                                                              int Ksrc, int Csrc) {
    __shared__ float tile[32][129];
    const int tid = threadIdx.x;
    const int mb = blockIdx.x, kb = blockIdx.y;
    const int K32 = Ksrc >> 5;
    #pragma unroll
    for (int i = 0; i < 4; i++) {
        int idx = tid + 256 * i;                 // 1024 float4 = 32 rows x 32
        int kl = idx >> 5, c4 = idx & 31;
        int n = mb * 128 + c4 * 4;
        float4 v = make_float4(0.f, 0.f, 0.f, 0.f);
        if (n < Csrc) v = *(const float4*)(src + (size_t)(kb * 32 + kl) * Csrc + n);
        tile[kl][c4 * 4 + 0] = v.x; tile[kl][c4 * 4 + 1] = v.y;
        tile[kl][c4 * 4 + 2] = v.z; tile[kl][c4 * 4 + 3] = v.w;
    }
    __syncthreads();
    #pragma unroll
    for (int i = 0; i < 2; i++) {
        int c = tid + 256 * i;                   // 512 granules
        int sub = c >> 6, ln = c & 63, q = ln >> 4, lmn = ln & 15;
        bf16x8 o;
        #pragma unroll
        for (int e = 0; e < 8; e++) o[e] = (__bf16)tile[q * 8 + e][sub * 16 + lmn];
        *(bf16x8*)(dst + ((((size_t)(mb * 8 + sub)) * K32 + kb) << 9) + (ln << 3)) = o;
    }
}

// ---------------- bf16 MFMA GEMM on TILED operands: C[M][N] = A * Bt^T --------------
// A tiled [M][K], Bt tiled [N][K]; staging is lane-contiguous; fragments lane-linear.
template<int STORE_BF16>
__global__ __launch_bounds__(256) void gemm_tt_kernel(const __bf16* __restrict__ A,
                                                      const __bf16* __restrict__ Bt,
                                                      float* __restrict__ Cf,
                                                      __bf16* __restrict__ Cb,
                                                      int N, int K) {
    __shared__ __align__(16) __bf16 As[4096];
    __shared__ __align__(16) __bf16 Bs[4096];
    const int tid = threadIdx.x;
    const int wave = tid >> 6, lane = tid & 63;
    const int lm = lane & 15, lq = lane >> 4;
    const int mb = blockIdx.x, nb = blockIdx.y;
    const int K32 = K >> 5;

    floatx4 acc[4][4] = {};

    for (int kb = 0; kb < K32; kb++) {
        #pragma unroll
        for (int r = 0; r < 2; r++) {
            int c = tid + (r << 8);              // 512 chunks of 16 B, lane-contiguous
            int sub = c >> 6, ln = c & 63;
            __builtin_amdgcn_global_load_lds(
                reinterpret_cast<const unsigned int*>(
                    A + ((((size_t)(mb * 8 + sub)) * K32 + kb) << 9) + (ln << 3)),
                reinterpret_cast<unsigned int*>(As + (size_t)c * 8), 16, 0, 0);
            __builtin_amdgcn_global_load_lds(
                reinterpret_cast<const unsigned int*>(
                    Bt + ((((size_t)(nb * 8 + sub)) * K32 + kb) << 9) + (ln << 3)),
                reinterpret_cast<unsigned int*>(Bs + (size_t)c * 8), 16, 0, 0);
        }
        __syncthreads();
        bf16x8 af[4], bfr[4];
        #pragma unroll
        for (int i = 0; i < 4; i++)
            af[i] = *(const bf16x8*)(As + ((((wave & 1) << 2) + i) << 9) + (lane << 3));
        #pragma unroll
        for (int i = 0; i < 4; i++)
            bfr[i] = *(const bf16x8*)(Bs + ((((wave >> 1) << 2) + i) << 9) + (lane << 3));
        #pragma unroll
        for (int mi = 0; mi < 4; mi++)
            #pragma unroll
            for (int ni = 0; ni < 4; ni++)
                acc[mi][ni] = __builtin_amdgcn_mfma_f32_16x16x32_bf16(af[mi], bfr[ni], acc[mi][ni], 0, 0, 0);
        __syncthreads();
    }

    const int wm = (wave & 1) << 6, wn = (wave >> 1) << 6;
    #pragma unroll
    for (int mi = 0; mi < 4; mi++) {
        #pragma unroll
        for (int r = 0; r < 4; r++) {
            int row = mb * 128 + wm + mi * 16 + lq * 4 + r;
            #pragma unroll
            for (int ni = 0; ni < 4; ni++) {
                int col = nb * 128 + wn + ni * 16 + lm;
                if (col < N) {
                    if (STORE_BF16) Cb[(size_t)row * N + col] = (__bf16)acc[mi][ni][r];
                    else            Cf[(size_t)row * N + col] = acc[mi][ni][r];
                }
            }
        }
    }
}

// ---------------- depthwise causal conv (width 4) + silu, vectorized bf16x8 ----------
__global__ __launch_bounds__(256) void conv_silu_kernel(const __bf16* __restrict__ zx,
                                                        const float* __restrict__ cw,
                                                        const float* __restrict__ cb,
                                                        __bf16* __restrict__ out) {
    const int tid = threadIdx.x;
    const int tc = tid & 15, tt = tid >> 4;
    const int c0 = (blockIdx.x * 16 + tc) * 8;      // 0..2168
    const int tg = blockIdx.y * 16 + tt;            // 0..1023
    const int b = tg >> 8, t0 = (tg & 255) << 3;

    float xb[11][8];
    #pragma unroll
    for (int i = 0; i < 11; i++) {
        int t = t0 + i - 3;
        if (t >= 0) {
            bf16x8 v = *(const bf16x8*)(zx + ((size_t)(b * SEQ + t)) * DPROJ + DIN + c0);
            #pragma unroll
            for (int j = 0; j < 8; j++) xb[i][j] = (float)v[j];
        } else {
            #pragma unroll
            for (int j = 0; j < 8; j++) xb[i][j] = 0.f;
        }
    }
    float w0[8], w1[8], w2[8], w3[8], bias[8];
    #pragma unroll
    for (int j = 0; j < 8; j++) {
        float4 w = *(const float4*)(cw + (size_t)(c0 + j) * 4);
        w0[j] = w.x; w1[j] = w.y; w2[j] = w.z; w3[j] = w.w;
        bias[j] = cb[c0 + j];
    }
    #pragma unroll
    for (int s = 0; s < 8; s++) {
        bf16x8 o;
        #pragma unroll
        for (int j = 0; j < 8; j++) {
            float v = bias[j] + w0[j] * xb[s][j] + w1[j] * xb[s + 1][j]
                              + w2[j] * xb[s + 2][j] + w3[j] * xb[s + 3][j];
            o[j] = (__bf16)(v / (1.f + __expf(-v)));
        }
        *(bf16x8*)(out + ((size_t)(b * SEQ + t0 + s)) * CONVD + c0) = o;
    }
}

// ---------------- dt prep: softplus + per-chunk inclusive cumsum of dt*A ----------------
__global__ __launch_bounds__(256) void dt_prep_kernel(const float* __restrict__ dtraw,
                                                      const float* __restrict__ dt_bias,
                                                      const float* __restrict__ A_log,
                                                      float* __restrict__ dtv,
                                                      float* __restrict__ cum) {
    int blk = blockIdx.x;          // b*NH + h
    int b = blk >> 5, h = blk & 31;
    int wave = threadIdx.x >> 6, lane = threadIdx.x & 63;
    float Ah = -__expf(A_log[h]);
    float dtb = dt_bias[h];
    for (int c = wave; c < NC; c += 4) {
        int t = c * QC + lane;
        float u = dtraw[((size_t)b * SEQ + t) * NH + h] + dtb;
        float d = fmaxf(u, 0.f) + log1pf(__expf(-fabsf(u)));  // softplus, fp32
        float s = d * Ah;
        #pragma unroll
        for (int o = 1; o < 64; o <<= 1) {        // inclusive wave prefix sum
            float v = __shfl_up(s, o);
            if (lane >= o) s += v;
        }
        size_t idx = (size_t)blk * SEQ + t;
        dtv[idx] = d;
        cum[idx] = s;
    }
}

// ---------------- chunk state (MFMA): S^T[p][n] = sum_s x[s][p]*w_s*B[s][n] ----------
__global__ __launch_bounds__(256) void chunk_state_kernel(const __bf16* __restrict__ xc,
                                                          const float* __restrict__ dtv,
                                                          const float* __restrict__ cum,
                                                          __bf16* __restrict__ Sbuf) {
    const int blk = blockIdx.x;            // ((b*NC)+c)*8 + hq
    const int hq = blk & 7;
    const int bc = blk >> 3;
    const int c = bc & (NC - 1), b = bc >> 5;
    const int tid = threadIdx.x;
    const int wave = tid >> 6, lane = tid & 63;
    const int lm = lane & 15, q = lane >> 4;
    const int h = hq * 4 + wave;

    __shared__ __align__(16) __bf16 sBt[4096];      // B^T [n][s], swizzled
    __shared__ __align__(16) __bf16 sXw[4][4096];   // (w*x)^T [p][s], swizzled

    const size_t rowbase = (size_t)b * SEQ + (size_t)c * QC;
    {
        int k = tid & 31, n0 = (tid >> 5) * 8;
        unsigned short u0[8], u1[8];
        *(uint4*)u0 = *(const uint4*)(xc + (rowbase + 2 * k) * CONVD + DIN + n0);
        *(uint4*)u1 = *(const uint4*)(xc + (rowbase + 2 * k + 1) * CONVD + DIN + n0);
        #pragma unroll
        for (int i = 0; i < 8; i++) {
            unsigned int v = (unsigned int)u0[i] | ((unsigned int)u1[i] << 16);
            ((unsigned int*)sBt)[swz(n0 + i, 2 * k) >> 1] = v;
        }
    }
    const float* cump = cum + (size_t)(b * NH + h) * SEQ + (size_t)c * QC;
    const float* dtp  = dtv + (size_t)(b * NH + h) * SEQ + (size_t)c * QC;
    {
        int k = lane & 31, ph = (lane >> 5) * 32;
        float clast = cump[63];
        float w0 = dtp[2 * k]     * __expf(clast - cump[2 * k]);
        float w1 = dtp[2 * k + 1] * __expf(clast - cump[2 * k + 1]);
        unsigned short u0[32], u1[32];
        const __bf16* r0 = xc + (rowbase + 2 * k) * CONVD + h * 64 + ph;
        const __bf16* r1 = xc + (rowbase + 2 * k + 1) * CONVD + h * 64 + ph;
        #pragma unroll
        for (int i = 0; i < 4; i++) {
            ((uint4*)u0)[i] = ((const uint4*)r0)[i];
            ((uint4*)u1)[i] = ((const uint4*)r1)[i];
        }
        unsigned int* dstw = (unsigned int*)sXw[wave];
        #pragma unroll
        for (int i = 0; i < 32; i++) {
            unsigned int lo = f2bfbits(bfbits2f(u0[i]) * w0);
            unsigned int hi = f2bfbits(bfbits2f(u1[i]) * w1);
            dstw[swz(ph + i, 2 * k) >> 1] = lo | (hi << 16);
        }
    }
    __syncthreads();

    floatx4 acc[4][4] = {};
    #pragma unroll
    for (int kb = 0; kb < 2; kb++) {
        bf16x8 aX[4], bB[4];
        #pragma unroll
        for (int pi = 0; pi < 4; pi++)
            aX[pi] = *(const bf16x8*)(&sXw[wave][swz(pi * 16 + lm, kb * 32 + q * 8)]);
        #pragma unroll
        for (int ni = 0; ni < 4; ni++)
            bB[ni] = *(const bf16x8*)(&sBt[swz(ni * 16 + lm, kb * 32 + q * 8)]);
        #pragma unroll
        for (int pi = 0; pi < 4; pi++)
            #pragma unroll
            for (int ni = 0; ni < 4; ni++)
                acc[pi][ni] = __builtin_amdgcn_mfma_f32_16x16x32_bf16(aX[pi], bB[ni], acc[pi][ni], 0, 0, 0);
    }
    __bf16* Sp = Sbuf + ((size_t)(b * NC + c) * NH + h) * (HD * DST);
    #pragma unroll
    for (int pi = 0; pi < 4; pi++)
        #pragma unroll
        for (int r = 0; r < 4; r++) {
            int p = pi * 16 + q * 4 + r;
            #pragma unroll
            for (int ni = 0; ni < 4; ni++)
                Sp[p * 64 + ni * 16 + lm] = (__bf16)acc[pi][ni][r];
        }
}

// ---------------- pass 2: inter-chunk state recurrence (in place) ----------------
__global__ __launch_bounds__(256) void state_scan_kernel(__bf16* __restrict__ Sbuf,
                                                         const float* __restrict__ cum) {
    int blk = blockIdx.x;          // b*NH + h
    int b = blk >> 5, h = blk & 31;
    int off = threadIdx.x * 16;
    float run[16];
    #pragma unroll
    for (int n = 0; n < 16; n++) run[n] = 0.f;
    for (int c = 0; c < NC; c++) {
        __bf16* Sp = Sbuf + ((size_t)(b * NC + c) * NH + h) * (HD * DST) + off;
        float tmp[16];
        #pragma unroll
        for (int n = 0; n < 16; n++) tmp[n] = (float)Sp[n];
        #pragma unroll
        for (int n = 0; n < 16; n++) Sp[n] = (__bf16)run[n];   // slot c <- state before chunk c
        float P = __expf(cum[(size_t)blk * SEQ + c * QC + QC - 1]);
        #pragma unroll
        for (int n = 0; n < 16; n++) run[n] = fmaf(run[n], P, tmp[n]);
    }
}

// ---------------- chunk output (MFMA): Y = exp(cum_t)*C@S_prev + (M o C@B^T + D*I)@X
// block = (b,c,head-pair); wave = one head; 128 threads; stores into TILED yf.
__global__ __launch_bounds__(128) void chunk_out_kernel(const __bf16* __restrict__ xc,
                                                        const float* __restrict__ dtv,
                                                        const float* __restrict__ cum,
                                                        const __bf16* __restrict__ Sbuf,
                                                        const float* __restrict__ Dv,
                                                        __bf16* __restrict__ y) {
    const int blk = blockIdx.x;           // ((b*NC)+c)*16 + hp
    const int hp = blk & 15;
    const int bc = blk >> 4;
    const int c = bc & (NC - 1), b = bc >> 5;
    const int tid = threadIdx.x;
    const int wave = tid >> 6, lane = tid & 63;
    const int lm = lane & 15, q = lane >> 4;
    const int h = hp * 2 + wave;

    __shared__ __align__(16) __bf16 smem[16384];     // 32 KB
    __bf16* sB  = smem;                              // B [s][n] swizzled (shared)
    __bf16* sC  = smem + 4096;                       // C [t][n] swizzled (shared)
    __bf16* sXt = smem + 8192 + (wave << 12);        // x^T [p][s] swizzled (per wave)
    __bf16* sP  = smem + (wave << 12);               // P aliases sB (w0) / sC (w1)

    const size_t rowbase = (size_t)b * SEQ + (size_t)c * QC;
    {
        int r = tid >> 1, c0 = (tid & 1) * 32;
        const __bf16* gB = xc + (rowbase + r) * CONVD + DIN + c0;
        const __bf16* gC = xc + (rowbase + r) * CONVD + DIN + DST + c0;
        #pragma unroll
        for (int i = 0; i < 4; i++) {
            *(uint4*)(&sB[swz(r, c0 + i * 8)]) = *(const uint4*)(gB + i * 8);
            *(uint4*)(&sC[swz(r, c0 + i * 8)]) = *(const uint4*)(gC + i * 8);
        }
    }
    {
        int k = lane & 31, ph = (lane >> 5) * 32;
        unsigned short u0[32], u1[32];
        const __bf16* r0 = xc + (rowbase + 2 * k) * CONVD + h * 64 + ph;
        const __bf16* r1 = xc + (rowbase + 2 * k + 1) * CONVD + h * 64 + ph;
        #pragma unroll
        for (int i = 0; i < 4; i++) {
            ((uint4*)u0)[i] = ((const uint4*)r0)[i];
            ((uint4*)u1)[i] = ((const uint4*)r1)[i];
        }
        unsigned int* dstw = (unsigned int*)sXt;
        #pragma unroll
        for (int i = 0; i < 32; i++)
            dstw[swz(ph + i, 2 * k) >> 1] = (unsigned int)u0[i] | ((unsigned int)u1[i] << 16);
    }
    __syncthreads();

    const float* cump = cum + (size_t)(b * NH + h) * SEQ + (size_t)c * QC;
    const float* dtp  = dtv + (size_t)(b * NH + h) * SEQ + (size_t)c * QC;
    float cumv = cump[lane], dtvv = dtp[lane];
    float ct[4][4];
    #pragma unroll
    for (int ti = 0; ti < 4; ti++)
        #pragma unroll
        for (int r = 0; r < 4; r++)
            ct[ti][r] = __shfl(cumv, ti * 16 + q * 4 + r);
    float cums_l[4], dtv_l[4];
    #pragma unroll
    for (int si = 0; si < 4; si++) {
        cums_l[si] = __shfl(cumv, si * 16 + lm);
        dtv_l[si]  = __shfl(dtvv, si * 16 + lm);
    }

    // A-fragments of C (reused for G and inter GEMMs)
    bf16x8 afC[4][2];
    #pragma unroll
    for (int ti = 0; ti < 4; ti++)
        #pragma unroll
        for (int kb = 0; kb < 2; kb++)
            afC[ti][kb] = *(const bf16x8*)(&sC[swz(ti * 16 + lm, kb * 32 + q * 8)]);

    // G = C @ B^T (triangular tiles si<=ti)
    floatx4 accG[4][4] = {};
    #pragma unroll
    for (int kb = 0; kb < 2; kb++) {
        bf16x8 bfB[4];
        #pragma unroll
        for (int si = 0; si < 4; si++)
            bfB[si] = *(const bf16x8*)(&sB[swz(si * 16 + lm, kb * 32 + q * 8)]);
        #pragma unroll
        for (int ti = 0; ti < 4; ti++)
            #pragma unroll
            for (int si = 0; si < 4; si++)
                if (si <= ti)
                    accG[ti][si] = __builtin_amdgcn_mfma_f32_16x16x32_bf16(afC[ti][kb], bfB[si], accG[ti][si], 0, 0, 0);
    }
    __syncthreads();   // all waves done reading sB/sC -> safe to overwrite with P

    // mask + decay -> P (bf16, swizzled [t][s]); D folded onto the diagonal
    float Dh = Dv[h];
    #pragma unroll
    for (int ti = 0; ti < 4; ti++)
        #pragma unroll
        for (int si = 0; si < 4; si++) {
            if (si > ti) continue;
            #pragma unroll
            for (int r = 0; r < 4; r++) {
                int t = ti * 16 + q * 4 + r;
                float arg = fminf(ct[ti][r] - cums_l[si], 0.f);
                float val = dtv_l[si] * __expf(arg) * accG[ti][si][r];
                if (ti == si) {
                    if (lm > q * 4 + r) val = 0.f;
                    else if (lm == q * 4 + r) val += Dh;
                }
                sP[swz(t, si * 16 + lm)] = (__bf16)val;
            }
        }
    #pragma unroll
    for (int r = 0; r < 4; r++) {   // zero tiles (0,1) and (2,3)
        sP[swz(q * 4 + r, 16 + lm)] = (__bf16)0.f;
        sP[swz(32 + q * 4 + r, 48 + lm)] = (__bf16)0.f;
    }
    __syncthreads();

    // inter-chunk: Y = C @ S_prev, then row-scale by exp(cum_t)
    floatx4 accY[4][4] = {};
    const __bf16* Sp = Sbuf + ((size_t)(b * NC + c) * NH + h) * (HD * DST);
    #pragma unroll
    for (int kb = 0; kb < 2; kb++) {
        bf16x8 bS[4];
        #pragma unroll
        for (int pi = 0; pi < 4; pi++)
            bS[pi] = *(const bf16x8*)(Sp + (pi * 16 + lm) * 64 + kb * 32 + q * 8);
        #pragma unroll
        for (int ti = 0; ti < 4; ti++)
            #pragma unroll
            for (int pi = 0; pi < 4; pi++)
                accY[ti][pi] = __builtin_amdgcn_mfma_f32_16x16x32_bf16(afC[ti][kb], bS[pi], accY[ti][pi], 0, 0, 0);
    }
    #pragma unroll
    for (int ti = 0; ti < 4; ti++)
        #pragma unroll
        for (int r = 0; r < 4; r++) {
            float e = __expf(ct[ti][r]);
            #pragma unroll
            for (int pi = 0; pi < 4; pi++)
                accY[ti][pi][r] *= e;
        }

    // intra: Y += P @ X  (skip fully-masked k-blocks)
    #pragma unroll
    for (int kb = 0; kb < 2; kb++) {
        bf16x8 bX[4];
        #pragma unroll
        for (int pi = 0; pi < 4; pi++)
            bX[pi] = *(const bf16x8*)(&sXt[swz(pi * 16 + lm, kb * 32 + q * 8)]);
        #pragma unroll
        for (int ti = 0; ti < 4; ti++) {
            if (ti < 2 * kb) continue;
            bf16x8 aP = *(const bf16x8*)(&sP[swz(ti * 16 + lm, kb * 32 + q * 8)]);
            #pragma unroll
            for (int pi = 0; pi < 4; pi++)
                accY[ti][pi] = __builtin_amdgcn_mfma_f32_16x16x32_bf16(aP, bX[pi], accY[ti][pi], 0, 0, 0);
        }
    }

    // store into TILED yf [M=8192][K=2048] (slab index = global_row>>4, 32768 elems/slab)
    const int R4v = (int)(rowbase >> 4);
    #pragma unroll
    for (int ti = 0; ti < 4; ti++) {
        __bf16* slab = y + (size_t)(R4v + ti) * 32768;
        #pragma unroll
        for (int pi = 0; pi < 4; pi++) {
            int kbC = h * 2 + (pi >> 1);
            int qC  = ((pi & 1) << 1) + (lm >> 3);
            int colpart = kbC * 512 + qC * 128 + (lm & 7);
            #pragma unroll
            for (int r = 0; r < 4; r++)
                slab[colpart + (q * 4 + r) * 8] = (__bf16)accY[ti][pi][r];
        }
    }
}

// ---------------- gate (silu(z)) + RMSNorm, in place on TILED yf ----------------
// block = one 16-row slab (512 blocks); slab is linear: granule g at offset g*8,
// g = pos*16 + lm covers row lm, cols pos*8..+7.
__global__ __launch_bounds__(256) void gate_norm_kernel(__bf16* __restrict__ y,
                                                        const __bf16* __restrict__ zx,
                                                        const float* __restrict__ nw) {
    const int tid = threadIdx.x;
    const int lm = tid & 15;
    __bf16* yfb = y + (size_t)blockIdx.x * 32768;
    const size_t zrow = ((size_t)blockIdx.x * 16 + lm) * DPROJ;

    float ss = 0.f;
    #pragma unroll
    for (int i = 0; i < 16; i++) {
        int g = tid + 256 * i;
        int pos = g >> 4;
        bf16x8 yv = *(const bf16x8*)(yfb + (size_t)g * 8);
        bf16x8 zv = *(const bf16x8*)(zx + zrow + pos * 8);
        #pragma unroll
        for (int j = 0; j < 8; j++) {
            float z = (float)zv[j];
            float val = (float)yv[j] * (z / (1.f + __expf(-z)));
            ss += val * val;
        }
    }
    __shared__ float red[16][16];
    __shared__ float sscale[16];
    red[lm][tid >> 4] = ss;
    __syncthreads();
    if (tid < 16) {
        float tot = 0.f;
        #pragma unroll
        for (int j = 0; j < 16; j++) tot += red[tid][j];
        sscale[tid] = rsqrtf(tot * (1.f / (float)DIN) + 1e-5f);
    }
    __syncthreads();
    float sc = sscale[lm];
    #pragma unroll
    for (int i = 0; i < 16; i++) {
        int g = tid + 256 * i;
        int pos = g >> 4;
        bf16x8 yv = *(const bf16x8*)(yfb + (size_t)g * 8);
        bf16x8 zv = *(const bf16x8*)(zx + zrow + pos * 8);
        float4 n0 = *(const float4*)(nw + pos * 8);
        float4 n1 = *(const float4*)(nw + pos * 8 + 4);
        float nwv[8] = {n0.x, n0.y, n0.z, n0.w, n1.x, n1.y, n1.z, n1.w};
        bf16x8 o;
        #pragma unroll
        for (int j = 0; j < 8; j++) {
            float z = (float)zv[j];
            float val = (float)yv[j] * (z / (1.f + __expf(-z)));
            o[j] = (__bf16)(val * sc * nwv[j]);
        }
        *(bf16x8*)(yfb + (size_t)g * 8) = o;
    }
}

// ---------------- launch ----------------
extern "C" void kernel_launch(void* const* d_in, const int* in_sizes, int n_in,
                              void* d_out, int out_size, void* d_ws, size_t ws_size,
                              hipStream_t stream) {
    const float* x       = (const float*)d_in[0];
    const float* W_in    = (const float*)d_in[1];
    const float* conv_w  = (const float*)d_in[2];
    const float* conv_b  = (const float*)d_in[3];
    const float* dt_bias = (const float*)d_in[4];
    const float* A_log   = (const float*)d_in[5];
    const float* Dv      = (const float*)d_in[6];
    const float* norm_w  = (const float*)d_in[7];
    const float* W_out   = (const float*)d_in[8];
    float* out = (float*)d_out;

    char* ws = (char*)d_ws;
    size_t off = 0;
    auto take = [&](size_t bytes) { void* p = ws + off; off = (off + bytes + 255) & ~(size_t)255; return p; };
    __bf16* xbf    = (__bf16*)take((size_t)MROWS * DM * 2);          // 16.8 MB (tiled)
    __bf16* WinT   = (__bf16*)take((size_t)NPAD1 * DM * 2);          //  8.9 MB (tiled)
    __bf16* WoutT  = (__bf16*)take((size_t)DM * DIN * 2);            //  4.2 MB (tiled)
    __bf16* zx     = (__bf16*)take((size_t)MROWS * DPROJ * 2);       // 69.7 MB (row-major)
    __bf16* xc     = (__bf16*)take((size_t)MROWS * CONVD * 2);       // 35.7 MB (row-major)
    __bf16* yf     = (__bf16*)take((size_t)MROWS * DIN * 2);         // 33.6 MB (tiled)
    float*  dtraw  = (float*) take((size_t)MROWS * NH * 4);          //  1.0 MB
    float*  dtv    = (float*) take((size_t)B_SZ * NH * SEQ * 4);     //  1.0 MB
    float*  cum    = (float*) take((size_t)B_SZ * NH * SEQ * 4);     //  1.0 MB
    __bf16* Sbuf   = (__bf16*)take((size_t)B_SZ * NC * NH * HD * DST * 2); // 33.6 MB
    float*  dtWc   = (float*) take((size_t)DM * NH * 4);             //  0.13 MB
    (void)ws_size;                                                    // total ~206 MB

    // 1. compact dt-weight
    dtw_prep_kernel<<<dim3(DM * NH / 256), 256, 0, stream>>>(W_in, dtWc);
    // 2. fused x->tiled bf16 + fp32 dt projection (512 slabs)
    cvt_dt_kernel<<<dim3(MROWS / 16), 256, 0, stream>>>(x, dtWc, xbf, dtraw);
    // 3. tiled W_in^T (pad to 4352 rows), tiled W_out^T
    transpose_tiled_kernel<<<dim3(NPAD1 / 128, DM / 32), 256, 0, stream>>>(W_in, WinT, DM, DPROJ);
    transpose_tiled_kernel<<<dim3(DM / 128, DIN / 32), 256, 0, stream>>>(W_out, WoutT, DIN, DM);
    // 4. GEMM1: zx = x @ W_in  (bf16 out, row-major)
    gemm_tt_kernel<1><<<dim3(MROWS / 128, NPAD1 / 128), 256, 0, stream>>>(
        xbf, WinT, nullptr, zx, DPROJ, DM);
    // 5. depthwise conv + silu (vectorized)
    conv_silu_kernel<<<dim3(17, 64), 256, 0, stream>>>(zx, conv_w, conv_b, xc);
    // 6. dt prep: softplus + per-chunk cumsum
    dt_prep_kernel<<<dim3(B_SZ * NH), 256, 0, stream>>>(dtraw, dt_bias, A_log, dtv, cum);
    // 7. chunk-local states via MFMA (1024 blocks x 4 waves)
    chunk_state_kernel<<<dim3(B_SZ * NC * (NH / 4)), 256, 0, stream>>>(xc, dtv, cum, Sbuf);
    // 8. inter-chunk state recurrence
    state_scan_kernel<<<dim3(B_SZ * NH), 256, 0, stream>>>(Sbuf, cum);
    // 9. chunk outputs via MFMA -> tiled yf (2048 blocks x 2 waves)
    chunk_out_kernel<<<dim3(B_SZ * NC * (NH / 2)), 128, 0, stream>>>(xc, dtv, cum, Sbuf, Dv, yf);
    // 10. gate + RMSNorm (in place on tiled yf, 512 slabs)
    gate_norm_kernel<<<dim3(MROWS / 16), 256, 0, stream>>>(yf, zx, norm_w);
    // 11. GEMM2: out = yf @ W_out (fp32 out, row-major)
    gemm_tt_kernel<0><<<dim3(MROWS / 128, DM / 128), 256, 0, stream>>>(
        yf, WoutT, out, nullptr, DM, DIN);
}

// Round 8
// 379.560 us; speedup vs baseline: 1.1852x; 1.0615x over previous
//
#include <hip/hip_runtime.h>
#include <hip/hip_bf16.h>

// ---------------- constants ----------------
#define B_SZ   4
#define SEQ    2048
#define DM     1024
#define DIN    2048
#define DST    64
#define NH     32
#define HD     64
#define CONVD  2176
#define DPROJ  4256   // 2*DIN + 2*DST + NH (source W_in width)
#define NPROJ  4224   // z + xBC only = 33*128 (dt cols excluded from GEMM1)
#define MROWS  (B_SZ*SEQ)  // 8192
#define QC     64     // scan chunk length
#define NC     (SEQ/QC)   // 32 chunks

// Tiled operand layout for MFMA GEMMs ("fragment order"):
//   flat(r,k) = (((r>>4)*(K>>5) + (k>>5))*64 + ((k>>3)&3)*16 + (r&15))*8 + (k&7)
// => each (16-row, 32-col) tile is 512 contiguous elems, lane-linear for both
//    global_load_lds staging and ds_read_b128 fragment reads.

typedef __attribute__((ext_vector_type(8))) __bf16 bf16x8;
typedef __attribute__((ext_vector_type(4))) __bf16 bf16x4;
typedef __attribute__((ext_vector_type(4))) float  floatx4;

// XOR-swizzled index into a 64x64 bf16 LDS tile (8-elem granules rotated by row&7)
__device__ __forceinline__ int swz(int row, int col) {
    return row * 64 + ((((col >> 3) ^ (row & 7)) << 3) | (col & 7));
}
__device__ __forceinline__ float bfbits2f(unsigned short u) {
    return __uint_as_float(((unsigned int)u) << 16);
}
__device__ __forceinline__ unsigned short f2bfbits(float f) {
    union { __bf16 h; unsigned short u; } cv; cv.h = (__bf16)f; return cv.u;
}

// ---------------- merged weight prep: dtWc compaction + 2 tiled transposes ----------
// grid: [0,128) dtw | [128,1184) W_in^T (33x32) | [1184,1696) W_out^T*norm_w (8x64)
__global__ __launch_bounds__(256) void prep_weights_kernel(const float* __restrict__ W_in,
                                                           const float* __restrict__ W_out,
                                                           const float* __restrict__ norm_w,
                                                           float* __restrict__ dtWc,
                                                           __bf16* __restrict__ WinT,
                                                           __bf16* __restrict__ WoutT) {
    __shared__ float tile[32][129];
    const int bid = blockIdx.x, tid = threadIdx.x;
    if (bid < 128) {
        int idx = bid * 256 + tid;
        int k = idx >> 5, h = idx & 31;
        dtWc[idx] = W_in[(size_t)k * DPROJ + 2 * DIN + 2 * DST + h];
        return;
    }
    const float* src; __bf16* dst; const float* scal; int Ksrc, Csrc, mb, kb;
    if (bid < 128 + 1056) {
        int t = bid - 128; mb = t >> 5; kb = t & 31;
        src = W_in; dst = WinT; scal = nullptr; Ksrc = DM; Csrc = DPROJ;
    } else {
        int t = bid - 1184; mb = t >> 6; kb = t & 63;
        src = W_out; dst = WoutT; scal = norm_w; Ksrc = DIN; Csrc = DM;
    }
    const int K32 = Ksrc >> 5;
    #pragma unroll
    for (int i = 0; i < 4; i++) {
        int idx = tid + 256 * i;                 // 1024 float4 = 32 rows x 128 cols
        int kl = idx >> 5, c4 = idx & 31;
        int n = mb * 128 + c4 * 4;
        float4 v = make_float4(0.f, 0.f, 0.f, 0.f);
        if (n < Csrc) v = *(const float4*)(src + (size_t)(kb * 32 + kl) * Csrc + n);
        if (scal) { float s = scal[kb * 32 + kl]; v.x *= s; v.y *= s; v.z *= s; v.w *= s; }
        tile[kl][c4 * 4 + 0] = v.x; tile[kl][c4 * 4 + 1] = v.y;
        tile[kl][c4 * 4 + 2] = v.z; tile[kl][c4 * 4 + 3] = v.w;
    }
    __syncthreads();
    #pragma unroll
    for (int i = 0; i < 2; i++) {
        int c = tid + 256 * i;                   // 512 granules
        int sub = c >> 6, ln = c & 63, q = ln >> 4, lmn = ln & 15;
        bf16x8 o;
        #pragma unroll
        for (int e = 0; e < 8; e++) o[e] = (__bf16)tile[q * 8 + e][sub * 16 + lmn];
        *(bf16x8*)(dst + ((((size_t)(mb * 8 + sub)) * K32 + kb) << 9) + (ln << 3)) = o;
    }
}

// ---------------- fused: x -> TILED bf16 copy + fp32 dt projection ----------------
__global__ __launch_bounds__(256) void cvt_dt_kernel(const float* __restrict__ x,
                                                     const float* __restrict__ dtWc,
                                                     __bf16* __restrict__ xbf,
                                                     float* __restrict__ dtraw) {
    __shared__ float xs[16][132];
    __shared__ float dtw[128 * 32];
    const int tid = threadIdx.x;
    const int r0 = blockIdx.x * 16;
    const int lm = tid & 15, pos = tid >> 4;              // granule writer mapping
    const int rr = tid >> 4, h2 = (tid & 15) * 2;         // dt accumulator mapping
    __bf16* slab = xbf + (size_t)blockIdx.x * (16 * DM);  // slab = 16*K contiguous

    float a0 = 0.f, a1 = 0.f;
    for (int kc = 0; kc < 8; kc++) {
        #pragma unroll
        for (int i = 0; i < 2; i++) {
            int idx = tid + 256 * i;                       // 512 float4
            int row = idx >> 5, c4 = idx & 31;
            float4 v = ((const float4*)(x + (size_t)(r0 + row) * DM + kc * 128))[c4];
            xs[row][c4 * 4 + 0] = v.x; xs[row][c4 * 4 + 1] = v.y;
            xs[row][c4 * 4 + 2] = v.z; xs[row][c4 * 4 + 3] = v.w;
        }
        #pragma unroll
        for (int i = 0; i < 16; i++)
            dtw[tid + 256 * i] = dtWc[kc * 4096 + tid + 256 * i];
        __syncthreads();
        {
            bf16x8 o;
            #pragma unroll
            for (int e = 0; e < 8; e++) o[e] = (__bf16)xs[lm][pos * 8 + e];
            int kb = kc * 4 + (pos >> 2), q = pos & 3;
            *(bf16x8*)(slab + (size_t)(kb * 64 + q * 16 + lm) * 8) = o;
        }
        for (int j = 0; j < 128; j++) {
            float xv = xs[rr][j];
            a0 = fmaf(xv, dtw[j * 32 + h2], a0);
            a1 = fmaf(xv, dtw[j * 32 + h2 + 1], a1);
        }
        __syncthreads();
    }
    dtraw[(size_t)(r0 + rr) * NH + h2]     = a0;
    dtraw[(size_t)(r0 + rr) * NH + h2 + 1] = a1;
}

// ---------------- bf16 MFMA GEMM on TILED operands: C[M][N] = A * Bt^T --------------
// rowscale != nullptr: multiply output row m by rsqrt(rowscale[m]/DIN + 1e-5) (RMSNorm)
template<int STORE_BF16>
__global__ __launch_bounds__(256) void gemm_tt_kernel(const __bf16* __restrict__ A,
                                                      const __bf16* __restrict__ Bt,
                                                      float* __restrict__ Cf,
                                                      __bf16* __restrict__ Cb,
                                                      const float* __restrict__ rowscale,
                                                      int N, int K) {
    __shared__ __align__(16) __bf16 As[4096];
    __shared__ __align__(16) __bf16 Bs[4096];
    const int tid = threadIdx.x;
    const int wave = tid >> 6, lane = tid & 63;
    const int lm = lane & 15, lq = lane >> 4;
    const int mb = blockIdx.x, nb = blockIdx.y;
    const int K32 = K >> 5;

    floatx4 acc[4][4] = {};

    for (int kb = 0; kb < K32; kb++) {
        #pragma unroll
        for (int r = 0; r < 2; r++) {
            int c = tid + (r << 8);              // 512 chunks of 16 B, lane-contiguous
            int sub = c >> 6, ln = c & 63;
            __builtin_amdgcn_global_load_lds(
                reinterpret_cast<const unsigned int*>(
                    A + ((((size_t)(mb * 8 + sub)) * K32 + kb) << 9) + (ln << 3)),
                reinterpret_cast<unsigned int*>(As + (size_t)c * 8), 16, 0, 0);
            __builtin_amdgcn_global_load_lds(
                reinterpret_cast<const unsigned int*>(
                    Bt + ((((size_t)(nb * 8 + sub)) * K32 + kb) << 9) + (ln << 3)),
                reinterpret_cast<unsigned int*>(Bs + (size_t)c * 8), 16, 0, 0);
        }
        __syncthreads();
        bf16x8 af[4], bfr[4];
        #pragma unroll
        for (int i = 0; i < 4; i++)
            af[i] = *(const bf16x8*)(As + ((((wave & 1) << 2) + i) << 9) + (lane << 3));
        #pragma unroll
        for (int i = 0; i < 4; i++)
            bfr[i] = *(const bf16x8*)(Bs + ((((wave >> 1) << 2) + i) << 9) + (lane << 3));
        #pragma unroll
        for (int mi = 0; mi < 4; mi++)
            #pragma unroll
            for (int ni = 0; ni < 4; ni++)
                acc[mi][ni] = __builtin_amdgcn_mfma_f32_16x16x32_bf16(af[mi], bfr[ni], acc[mi][ni], 0, 0, 0);
        __syncthreads();
    }

    const int wm = (wave & 1) << 6, wn = (wave >> 1) << 6;
    #pragma unroll
    for (int mi = 0; mi < 4; mi++) {
        #pragma unroll
        for (int r = 0; r < 4; r++) {
            int row = mb * 128 + wm + mi * 16 + lq * 4 + r;
            float s = 1.f;
            if (rowscale) s = rsqrtf(rowscale[row] * (1.f / (float)DIN) + 1e-5f);
            #pragma unroll
            for (int ni = 0; ni < 4; ni++) {
                int col = nb * 128 + wn + ni * 16 + lm;
                if (col < N) {
                    if (STORE_BF16) Cb[(size_t)row * N + col] = (__bf16)acc[mi][ni][r];
                    else            Cf[(size_t)row * N + col] = acc[mi][ni][r] * s;
                }
            }
        }
    }
}

// ---------------- merged: conv+silu | dt_prep | rowsum zeroing ----------------
// grid: [0,1088) conv (17 x 64) | [1088,1216) dt_prep | [1216,1224) zero rowsum
__global__ __launch_bounds__(256) void conv_dt_kernel(const __bf16* __restrict__ zx,
                                                      const float* __restrict__ cw,
                                                      const float* __restrict__ cb,
                                                      __bf16* __restrict__ out,
                                                      const float* __restrict__ dtraw,
                                                      const float* __restrict__ dt_bias,
                                                      const float* __restrict__ A_log,
                                                      float* __restrict__ dtv,
                                                      float* __restrict__ cum,
                                                      float* __restrict__ rowsum) {
    const int bid = blockIdx.x, tid = threadIdx.x;
    if (bid < 1088) {
        // ---- depthwise causal conv (width 4) + silu, bf16x8 vectorized ----
        const int by = bid / 17, bx = bid - by * 17;
        const int tc = tid & 15, tt = tid >> 4;
        const int c0 = (bx * 16 + tc) * 8;              // 0..2168
        const int tg = by * 16 + tt;                    // 0..1023
        const int b = tg >> 8, t0 = (tg & 255) << 3;

        float xb[11][8];
        #pragma unroll
        for (int i = 0; i < 11; i++) {
            int t = t0 + i - 3;
            if (t >= 0) {
                bf16x8 v = *(const bf16x8*)(zx + ((size_t)(b * SEQ + t)) * NPROJ + DIN + c0);
                #pragma unroll
                for (int j = 0; j < 8; j++) xb[i][j] = (float)v[j];
            } else {
                #pragma unroll
                for (int j = 0; j < 8; j++) xb[i][j] = 0.f;
            }
        }
        float w0[8], w1[8], w2[8], w3[8], bias[8];
        #pragma unroll
        for (int j = 0; j < 8; j++) {
            float4 w = *(const float4*)(cw + (size_t)(c0 + j) * 4);
            w0[j] = w.x; w1[j] = w.y; w2[j] = w.z; w3[j] = w.w;
            bias[j] = cb[c0 + j];
        }
        #pragma unroll
        for (int s = 0; s < 8; s++) {
            bf16x8 o;
            #pragma unroll
            for (int j = 0; j < 8; j++) {
                float v = bias[j] + w0[j] * xb[s][j] + w1[j] * xb[s + 1][j]
                                  + w2[j] * xb[s + 2][j] + w3[j] * xb[s + 3][j];
                o[j] = (__bf16)(v / (1.f + __expf(-v)));
            }
            *(bf16x8*)(out + ((size_t)(b * SEQ + t0 + s)) * CONVD + c0) = o;
        }
    } else if (bid < 1216) {
        // ---- dt prep: softplus + per-chunk inclusive cumsum of dt*A ----
        const int blk = bid - 1088;    // b*NH + h
        const int b = blk >> 5, h = blk & 31;
        const int wave = tid >> 6, lane = tid & 63;
        float Ah = -__expf(A_log[h]);
        float dtb = dt_bias[h];
        for (int c = wave; c < NC; c += 4) {
            int t = c * QC + lane;
            float u = dtraw[((size_t)b * SEQ + t) * NH + h] + dtb;
            float d = fmaxf(u, 0.f) + log1pf(__expf(-fabsf(u)));  // softplus, fp32
            float s = d * Ah;
            #pragma unroll
            for (int o = 1; o < 64; o <<= 1) {
                float v = __shfl_up(s, o);
                if (lane >= o) s += v;
            }
            size_t idx = (size_t)blk * SEQ + t;
            dtv[idx] = d;
            cum[idx] = s;
        }
    } else {
        // ---- zero rowsum (8 blocks x 256 threads x 4 floats) ----
        float4 z = make_float4(0.f, 0.f, 0.f, 0.f);
        *(float4*)(rowsum + (size_t)(bid - 1216) * 1024 + tid * 4) = z;
    }
}

// ---------------- chunk state (MFMA): S^T[p][n] = sum_s x[s][p]*w_s*B[s][n] ----------
__global__ __launch_bounds__(256) void chunk_state_kernel(const __bf16* __restrict__ xc,
                                                          const float* __restrict__ dtv,
                                                          const float* __restrict__ cum,
                                                          __bf16* __restrict__ Sbuf) {
    const int blk = blockIdx.x;            // ((b*NC)+c)*8 + hq
    const int hq = blk & 7;
    const int bc = blk >> 3;
    const int c = bc & (NC - 1), b = bc >> 5;
    const int tid = threadIdx.x;
    const int wave = tid >> 6, lane = tid & 63;
    const int lm = lane & 15, q = lane >> 4;
    const int h = hq * 4 + wave;

    __shared__ __align__(16) __bf16 sBt[4096];      // B^T [n][s], swizzled
    __shared__ __align__(16) __bf16 sXw[4][4096];   // (w*x)^T [p][s], swizzled

    const size_t rowbase = (size_t)b * SEQ + (size_t)c * QC;
    {
        int k = tid & 31, n0 = (tid >> 5) * 8;
        unsigned short u0[8], u1[8];
        *(uint4*)u0 = *(const uint4*)(xc + (rowbase + 2 * k) * CONVD + DIN + n0);
        *(uint4*)u1 = *(const uint4*)(xc + (rowbase + 2 * k + 1) * CONVD + DIN + n0);
        #pragma unroll
        for (int i = 0; i < 8; i++) {
            unsigned int v = (unsigned int)u0[i] | ((unsigned int)u1[i] << 16);
            ((unsigned int*)sBt)[swz(n0 + i, 2 * k) >> 1] = v;
        }
    }
    const float* cump = cum + (size_t)(b * NH + h) * SEQ + (size_t)c * QC;
    const float* dtp  = dtv + (size_t)(b * NH + h) * SEQ + (size_t)c * QC;
    {
        int k = lane & 31, ph = (lane >> 5) * 32;
        float clast = cump[63];
        float w0 = dtp[2 * k]     * __expf(clast - cump[2 * k]);
        float w1 = dtp[2 * k + 1] * __expf(clast - cump[2 * k + 1]);
        unsigned short u0[32], u1[32];
        const __bf16* r0 = xc + (rowbase + 2 * k) * CONVD + h * 64 + ph;
        const __bf16* r1 = xc + (rowbase + 2 * k + 1) * CONVD + h * 64 + ph;
        #pragma unroll
        for (int i = 0; i < 4; i++) {
            ((uint4*)u0)[i] = ((const uint4*)r0)[i];
            ((uint4*)u1)[i] = ((const uint4*)r1)[i];
        }
        unsigned int* dstw = (unsigned int*)sXw[wave];
        #pragma unroll
        for (int i = 0; i < 32; i++) {
            unsigned int lo = f2bfbits(bfbits2f(u0[i]) * w0);
            unsigned int hi = f2bfbits(bfbits2f(u1[i]) * w1);
            dstw[swz(ph + i, 2 * k) >> 1] = lo | (hi << 16);
        }
    }
    __syncthreads();

    floatx4 acc[4][4] = {};
    #pragma unroll
    for (int kb = 0; kb < 2; kb++) {
        bf16x8 aX[4], bB[4];
        #pragma unroll
        for (int pi = 0; pi < 4; pi++)
            aX[pi] = *(const bf16x8*)(&sXw[wave][swz(pi * 16 + lm, kb * 32 + q * 8)]);
        #pragma unroll
        for (int ni = 0; ni < 4; ni++)
            bB[ni] = *(const bf16x8*)(&sBt[swz(ni * 16 + lm, kb * 32 + q * 8)]);
        #pragma unroll
        for (int pi = 0; pi < 4; pi++)
            #pragma unroll
            for (int ni = 0; ni < 4; ni++)
                acc[pi][ni] = __builtin_amdgcn_mfma_f32_16x16x32_bf16(aX[pi], bB[ni], acc[pi][ni], 0, 0, 0);
    }
    __bf16* Sp = Sbuf + ((size_t)(b * NC + c) * NH + h) * (HD * DST);
    #pragma unroll
    for (int pi = 0; pi < 4; pi++)
        #pragma unroll
        for (int r = 0; r < 4; r++) {
            int p = pi * 16 + q * 4 + r;
            #pragma unroll
            for (int ni = 0; ni < 4; ni++)
                Sp[p * 64 + ni * 16 + lm] = (__bf16)acc[pi][ni][r];
        }
}

// ---------------- pass 2: inter-chunk state recurrence (in place, 512 blocks) -------
__global__ __launch_bounds__(256) void state_scan_kernel(__bf16* __restrict__ Sbuf,
                                                         const float* __restrict__ cum) {
    int blk = blockIdx.x >> 2;     // b*NH + h
    int part = blockIdx.x & 3;
    int b = blk >> 5, h = blk & 31;
    int off = part * 1024 + threadIdx.x * 4;
    float run[4];
    #pragma unroll
    for (int n = 0; n < 4; n++) run[n] = 0.f;
    for (int c = 0; c < NC; c++) {
        __bf16* Sp = Sbuf + ((size_t)(b * NC + c) * NH + h) * (HD * DST) + off;
        bf16x4 sv = *(const bf16x4*)Sp;
        float tmp[4];
        #pragma unroll
        for (int n = 0; n < 4; n++) tmp[n] = (float)sv[n];
        bf16x4 ov;
        #pragma unroll
        for (int n = 0; n < 4; n++) ov[n] = (__bf16)run[n];
        *(bf16x4*)Sp = ov;                                  // slot c <- state before chunk c
        float P = __expf(cum[(size_t)blk * SEQ + c * QC + QC - 1]);
        #pragma unroll
        for (int n = 0; n < 4; n++) run[n] = fmaf(run[n], P, tmp[n]);
    }
}

// ---------------- chunk output (MFMA) + silu(z) gate + rowsum ----------------
// Y = exp(cum_t)*C@S_prev + (M o C@B^T + D*I)@X ; g = Y*silu(z) -> tiled yf; rowsum += g^2
__global__ __launch_bounds__(128) void chunk_out_kernel(const __bf16* __restrict__ xc,
                                                        const float* __restrict__ dtv,
                                                        const float* __restrict__ cum,
                                                        const __bf16* __restrict__ Sbuf,
                                                        const float* __restrict__ Dv,
                                                        const __bf16* __restrict__ zx,
                                                        float* __restrict__ rowsum,
                                                        __bf16* __restrict__ y) {
    const int blk = blockIdx.x;           // ((b*NC)+c)*16 + hp
    const int hp = blk & 15;
    const int bc = blk >> 4;
    const int c = bc & (NC - 1), b = bc >> 5;
    const int tid = threadIdx.x;
    const int wave = tid >> 6, lane = tid & 63;
    const int lm = lane & 15, q = lane >> 4;
    const int h = hp * 2 + wave;

    __shared__ __align__(16) __bf16 smem[16384];     // 32 KB
    __bf16* sB  = smem;                              // B [s][n] swizzled (shared)
    __bf16* sC  = smem + 4096;                       // C [t][n] swizzled (shared)
    __bf16* sXt = smem + 8192 + (wave << 12);        // x^T [p][s] swizzled (per wave)
    __bf16* sP  = smem + (wave << 12);               // P aliases sB (w0) / sC (w1)

    const size_t rowbase = (size_t)b * SEQ + (size_t)c * QC;
    {
        int r = tid >> 1, c0 = (tid & 1) * 32;
        const __bf16* gB = xc + (rowbase + r) * CONVD + DIN + c0;
        const __bf16* gC = xc + (rowbase + r) * CONVD + DIN + DST + c0;
        #pragma unroll
        for (int i = 0; i < 4; i++) {
            *(uint4*)(&sB[swz(r, c0 + i * 8)]) = *(const uint4*)(gB + i * 8);
            *(uint4*)(&sC[swz(r, c0 + i * 8)]) = *(const uint4*)(gC + i * 8);
        }
    }
    {
        int k = lane & 31, ph = (lane >> 5) * 32;
        unsigned short u0[32], u1[32];
        const __bf16* r0 = xc + (rowbase + 2 * k) * CONVD + h * 64 + ph;
        const __bf16* r1 = xc + (rowbase + 2 * k + 1) * CONVD + h * 64 + ph;
        #pragma unroll
        for (int i = 0; i < 4; i++) {
            ((uint4*)u0)[i] = ((const uint4*)r0)[i];
            ((uint4*)u1)[i] = ((const uint4*)r1)[i];
        }
        unsigned int* dstw = (unsigned int*)sXt;
        #pragma unroll
        for (int i = 0; i < 32; i++)
            dstw[swz(ph + i, 2 * k) >> 1] = (unsigned int)u0[i] | ((unsigned int)u1[i] << 16);
    }
    __syncthreads();

    const float* cump = cum + (size_t)(b * NH + h) * SEQ + (size_t)c * QC;
    const float* dtp  = dtv + (size_t)(b * NH + h) * SEQ + (size_t)c * QC;
    float cumv = cump[lane], dtvv = dtp[lane];
    float ct[4][4];
    #pragma unroll
    for (int ti = 0; ti < 4; ti++)
        #pragma unroll
        for (int r = 0; r < 4; r++)
            ct[ti][r] = __shfl(cumv, ti * 16 + q * 4 + r);
    float cums_l[4], dtv_l[4];
    #pragma unroll
    for (int si = 0; si < 4; si++) {
        cums_l[si] = __shfl(cumv, si * 16 + lm);
        dtv_l[si]  = __shfl(dtvv, si * 16 + lm);
    }

    bf16x8 afC[4][2];
    #pragma unroll
    for (int ti = 0; ti < 4; ti++)
        #pragma unroll
        for (int kb = 0; kb < 2; kb++)
            afC[ti][kb] = *(const bf16x8*)(&sC[swz(ti * 16 + lm, kb * 32 + q * 8)]);

    // G = C @ B^T (triangular tiles si<=ti)
    floatx4 accG[4][4] = {};
    #pragma unroll
    for (int kb = 0; kb < 2; kb++) {
        bf16x8 bfB[4];
        #pragma unroll
        for (int si = 0; si < 4; si++)
            bfB[si] = *(const bf16x8*)(&sB[swz(si * 16 + lm, kb * 32 + q * 8)]);
        #pragma unroll
        for (int ti = 0; ti < 4; ti++)
            #pragma unroll
            for (int si = 0; si < 4; si++)
                if (si <= ti)
                    accG[ti][si] = __builtin_amdgcn_mfma_f32_16x16x32_bf16(afC[ti][kb], bfB[si], accG[ti][si], 0, 0, 0);
    }
    __syncthreads();   // all waves done reading sB/sC -> safe to overwrite with P

    // mask + decay -> P (bf16, swizzled [t][s]); D folded onto the diagonal
    float Dh = Dv[h];
    #pragma unroll
    for (int ti = 0; ti < 4; ti++)
        #pragma unroll
        for (int si = 0; si < 4; si++) {
            if (si > ti) continue;
            #pragma unroll
            for (int r = 0; r < 4; r++) {
                int t = ti * 16 + q * 4 + r;
                float arg = fminf(ct[ti][r] - cums_l[si], 0.f);
                float val = dtv_l[si] * __expf(arg) * accG[ti][si][r];
                if (ti == si) {
                    if (lm > q * 4 + r) val = 0.f;
                    else if (lm == q * 4 + r) val += Dh;
                }
                sP[swz(t, si * 16 + lm)] = (__bf16)val;
            }
        }
    #pragma unroll
    for (int r = 0; r < 4; r++) {   // zero tiles (0,1) and (2,3)
        sP[swz(q * 4 + r, 16 + lm)] = (__bf16)0.f;
        sP[swz(32 + q * 4 + r, 48 + lm)] = (__bf16)0.f;
    }
    __syncthreads();

    // inter-chunk: Y = C @ S_prev, then row-scale by exp(cum_t)
    floatx4 accY[4][4] = {};
    const __bf16* Sp = Sbuf + ((size_t)(b * NC + c) * NH + h) * (HD * DST);
    #pragma unroll
    for (int kb = 0; kb < 2; kb++) {
        bf16x8 bS[4];
        #pragma unroll
        for (int pi = 0; pi < 4; pi++)
            bS[pi] = *(const bf16x8*)(Sp + (pi * 16 + lm) * 64 + kb * 32 + q * 8);
        #pragma unroll
        for (int ti = 0; ti < 4; ti++)
            #pragma unroll
            for (int pi = 0; pi < 4; pi++)
                accY[ti][pi] = __builtin_amdgcn_mfma_f32_16x16x32_bf16(afC[ti][kb], bS[pi], accY[ti][pi], 0, 0, 0);
    }
    #pragma unroll
    for (int ti = 0; ti < 4; ti++)
        #pragma unroll
        for (int r = 0; r < 4; r++) {
            float e = __expf(ct[ti][r]);
            #pragma unroll
            for (int pi = 0; pi < 4; pi++)
                accY[ti][pi][r] *= e;
        }

    // intra: Y += P @ X  (skip fully-masked k-blocks)
    #pragma unroll
    for (int kb = 0; kb < 2; kb++) {
        bf16x8 bX[4];
        #pragma unroll
        for (int pi = 0; pi < 4; pi++)
            bX[pi] = *(const bf16x8*)(&sXt[swz(pi * 16 + lm, kb * 32 + q * 8)]);
        #pragma unroll
        for (int ti = 0; ti < 4; ti++) {
            if (ti < 2 * kb) continue;
            bf16x8 aP = *(const bf16x8*)(&sP[swz(ti * 16 + lm, kb * 32 + q * 8)]);
            #pragma unroll
            for (int pi = 0; pi < 4; pi++)
                accY[ti][pi] = __builtin_amdgcn_mfma_f32_16x16x32_bf16(aP, bX[pi], accY[ti][pi], 0, 0, 0);
        }
    }

    // gate with silu(z), store into TILED yf, accumulate rowsum
    const int R4v = (int)(rowbase >> 4);
    #pragma unroll
    for (int ti = 0; ti < 4; ti++) {
        __bf16* slab = y + (size_t)(R4v + ti) * 32768;
        #pragma unroll
        for (int r = 0; r < 4; r++) {
            int t = ti * 16 + q * 4 + r;
            const __bf16* zrow = zx + (rowbase + t) * NPROJ + h * 64;
            float rs = 0.f;
            #pragma unroll
            for (int pi = 0; pi < 4; pi++) {
                float zv = (float)zrow[pi * 16 + lm];
                float g = accY[ti][pi][r] * (zv / (1.f + __expf(-zv)));
                rs += g * g;
                int kbC = h * 2 + (pi >> 1);
                int qC  = ((pi & 1) << 1) + (lm >> 3);
                slab[kbC * 512 + qC * 128 + (lm & 7) + (q * 4 + r) * 8] = (__bf16)g;
            }
            rs += __shfl_xor(rs, 1);
            rs += __shfl_xor(rs, 2);
            rs += __shfl_xor(rs, 4);
            rs += __shfl_xor(rs, 8);
            if (lm == 0) atomicAdd(&rowsum[rowbase + t], rs);
        }
    }
}

// ---------------- launch ----------------
extern "C" void kernel_launch(void* const* d_in, const int* in_sizes, int n_in,
                              void* d_out, int out_size, void* d_ws, size_t ws_size,
                              hipStream_t stream) {
    const float* x       = (const float*)d_in[0];
    const float* W_in    = (const float*)d_in[1];
    const float* conv_w  = (const float*)d_in[2];
    const float* conv_b  = (const float*)d_in[3];
    const float* dt_bias = (const float*)d_in[4];
    const float* A_log   = (const float*)d_in[5];
    const float* Dv      = (const float*)d_in[6];
    const float* norm_w  = (const float*)d_in[7];
    const float* W_out   = (const float*)d_in[8];
    float* out = (float*)d_out;

    char* ws = (char*)d_ws;
    size_t off = 0;
    auto take = [&](size_t bytes) { void* p = ws + off; off = (off + bytes + 255) & ~(size_t)255; return p; };
    __bf16* xbf    = (__bf16*)take((size_t)MROWS * DM * 2);          // 16.8 MB (tiled)
    __bf16* WinT   = (__bf16*)take((size_t)NPROJ * DM * 2);          //  8.7 MB (tiled)
    __bf16* WoutT  = (__bf16*)take((size_t)DM * DIN * 2);            //  4.2 MB (tiled, *norm_w)
    __bf16* zx     = (__bf16*)take((size_t)MROWS * NPROJ * 2);       // 69.2 MB (row-major)
    __bf16* xc     = (__bf16*)take((size_t)MROWS * CONVD * 2);       // 35.7 MB (row-major)
    __bf16* yf     = (__bf16*)take((size_t)MROWS * DIN * 2);         // 33.6 MB (tiled, gated)
    float*  dtraw  = (float*) take((size_t)MROWS * NH * 4);          //  1.0 MB
    float*  dtv    = (float*) take((size_t)B_SZ * NH * SEQ * 4);     //  1.0 MB
    float*  cum    = (float*) take((size_t)B_SZ * NH * SEQ * 4);     //  1.0 MB
    __bf16* Sbuf   = (__bf16*)take((size_t)B_SZ * NC * NH * HD * DST * 2); // 33.6 MB
    float*  dtWc   = (float*) take((size_t)DM * NH * 4);             //  0.13 MB
    float*  rowsum = (float*) take((size_t)MROWS * 4);               //  32 KB
    (void)ws_size;                                                    // total ~205 MB

    // 1. weight prep: dtWc + tiled W_in^T + tiled (W_out*norm_w)^T
    prep_weights_kernel<<<dim3(1696), 256, 0, stream>>>(W_in, W_out, norm_w, dtWc, WinT, WoutT);
    // 2. fused x->tiled bf16 + fp32 dt projection (512 slabs)
    cvt_dt_kernel<<<dim3(MROWS / 16), 256, 0, stream>>>(x, dtWc, xbf, dtraw);
    // 3. GEMM1: zx = x @ W_in[:, :4224]  (bf16 out, row-major)
    gemm_tt_kernel<1><<<dim3(MROWS / 128, NPROJ / 128), 256, 0, stream>>>(
        xbf, WinT, nullptr, zx, nullptr, NPROJ, DM);
    // 4. merged: conv+silu | dt softplus+cumsum | zero rowsum
    conv_dt_kernel<<<dim3(1224), 256, 0, stream>>>(zx, conv_w, conv_b, xc,
                                                   dtraw, dt_bias, A_log, dtv, cum, rowsum);
    // 5. chunk-local states via MFMA (1024 blocks x 4 waves)
    chunk_state_kernel<<<dim3(B_SZ * NC * (NH / 4)), 256, 0, stream>>>(xc, dtv, cum, Sbuf);
    // 6. inter-chunk state recurrence (512 blocks)
    state_scan_kernel<<<dim3(B_SZ * NH * 4), 256, 0, stream>>>(Sbuf, cum);
    // 7. chunk outputs via MFMA + gate + rowsum -> tiled yf (2048 blocks x 2 waves)
    chunk_out_kernel<<<dim3(B_SZ * NC * (NH / 2)), 128, 0, stream>>>(
        xc, dtv, cum, Sbuf, Dv, zx, rowsum, yf);
    // 8. GEMM2: out = rmsnorm-scale(yf) @ (W_out*norm_w) (fp32 out)
    gemm_tt_kernel<0><<<dim3(MROWS / 128, DM / 128), 256, 0, stream>>>(
        yf, WoutT, out, nullptr, rowsum, DM, DIN);
}